// Round 4
// baseline (349.927 us; speedup 1.0000x reference)
//
#include <hip/hip_runtime.h>
#include <math.h>

#define TT 8
#define NTOK 12288
#define DD 256
#define NNODE 8192
#define NNODES 32768
#define CLEN 16
#define CDIM 64
#define CHUNK 2048
#define H1 128

__device__ __forceinline__ float gelu_exact(float v) {
    return 0.5f * v * (1.0f + erff(v * 0.70710678118654752f));
}

// ---- Kernel 0: G[c] = sum_k g[k]*w1[k,c]; B[c] = sum_k b[k]*w1[k,c] ----
__global__ __launch_bounds__(256) void k_prep(
    const float* __restrict__ ln1_g, const float* __restrict__ ln1_b,
    const float* __restrict__ w1, float* __restrict__ Gv, float* __restrict__ Bv)
{
    const int c = threadIdx.x & 127, h = threadIdx.x >> 7;
    __shared__ float gs[2][128], bs[2][128];
    float G = 0.f, B = 0.f;
    for (int k = h * 128; k < h * 128 + 128; ++k) {
        const float w = w1[(size_t)k * H1 + c];
        G += ln1_g[k] * w;
        B += ln1_b[k] * w;
    }
    gs[h][c] = G; bs[h][c] = B;
    __syncthreads();
    if (threadIdx.x < 128) {
        Gv[c] = gs[0][c] + gs[1][c];
        Bv[c] = bs[0][c] + bs[1][c];
    }
}

// ---- Kernel 1: x @ (g.*w1) with LN folded into epilogue; record rows per node ----
// grid (64 rowblocks, 8 t), block 256. Tile: 128 rows x 128 cols, BK=32, 8x8 microtile.
__global__ __launch_bounds__(256) void k_ln_gemm(
    const float* __restrict__ x, const int* __restrict__ indices,
    const float* __restrict__ ln1_g, const float* __restrict__ w1,
    const float* __restrict__ Gv, const float* __restrict__ Bv,
    float* __restrict__ y,
    int* __restrict__ cnt, int* __restrict__ slot0, int* __restrict__ slotsx,
    int* __restrict__ ovfcnt, int* __restrict__ ovf)
{
    const int t = blockIdx.y;
    const int rowBase = blockIdx.x * 128;
    const int tid = threadIdx.x;

    __shared__ float As[128 * 37];     // [row][k], stride 37 (bank-spread)
    __shared__ float Bs[32 * 132];     // [k][col], stride 132
    __shared__ float mS[128], rS[128];
    __shared__ float GS[128], BS[128];
    __shared__ float red[128][2][2];

    const float* xblk = x + ((size_t)t * NTOK + rowBase) * DD;

    // per-node row recording (128 rows of this block)
    if (tid < 128) {
        const int i = rowBase + tid;
        const int node = indices[t * NNODE + i];
        const int g = t * NNODES + node;
        const int pos = atomicAdd(&cnt[g], 1);
        if (pos == 0) slot0[g] = i;
        else if (pos <= 15) slotsx[(size_t)g * 15 + (pos - 1)] = i;
        else {
            const int op = atomicAdd(&ovfcnt[t], 1);
            ovf[t * NNODE + op] = (node << 13) | i;
        }
        GS[tid] = Gv[tid];
        BS[tid] = Bv[tid];
    }

    // LN stats (2 threads per row)
    {
        const int row = tid >> 1, q = tid & 1;
        const float* xr = xblk + (size_t)row * DD + q * 4;
        float s = 0.f, ss = 0.f;
        #pragma unroll
        for (int u = 0; u < 32; ++u) {
            const float4 v = *(const float4*)(xr + u * 8);
            s  += v.x + v.y + v.z + v.w;
            ss += v.x*v.x + v.y*v.y + v.z*v.z + v.w*v.w;
        }
        red[row][q][0] = s;
        red[row][q][1] = ss;
    }
    __syncthreads();
    if (tid < 128) {
        const float s  = red[tid][0][0] + red[tid][1][0];
        const float ss = red[tid][0][1] + red[tid][1][1];
        const float m = s * (1.0f / 256.0f);
        const float var = ss * (1.0f / 256.0f) - m * m;
        mS[tid] = m;
        rS[tid] = rsqrtf(var + 1e-5f);
    }
    __syncthreads();

    const int ty = tid >> 4;   // rows ty*8 .. ty*8+7
    const int tx = tid & 15;   // cols tx*4..+3 and 64+tx*4..+3
    float acc[8][8];
    #pragma unroll
    for (int j = 0; j < 8; ++j)
        #pragma unroll
        for (int jj = 0; jj < 8; ++jj) acc[j][jj] = 0.f;

    for (int kt = 0; kt < 8; ++kt) {
        // stage A (raw x) 128x32
        #pragma unroll
        for (int u = 0; u < 4; ++u) {
            const int f = tid + u * 256;
            const int row = f >> 3, c4 = f & 7;
            const float4 v = *(const float4*)(xblk + (size_t)row * DD + kt * 32 + c4 * 4);
            float* d = &As[37 * row + 4 * c4];
            d[0] = v.x; d[1] = v.y; d[2] = v.z; d[3] = v.w;
        }
        // stage B = g[k] * w1[k, :]
        #pragma unroll
        for (int u = 0; u < 4; ++u) {
            const int f = tid + u * 256;
            const int k = f >> 5, c4 = f & 31;
            float4 v = *(const float4*)(w1 + (size_t)(kt * 32 + k) * H1 + c4 * 4);
            const float gk = ln1_g[kt * 32 + k];
            v.x *= gk; v.y *= gk; v.z *= gk; v.w *= gk;
            *(float4*)&Bs[132 * k + 4 * c4] = v;
        }
        __syncthreads();
        #pragma unroll
        for (int k = 0; k < 32; ++k) {
            float a[8];
            #pragma unroll
            for (int j = 0; j < 8; ++j) a[j] = As[37 * (8 * ty + j) + k];
            const float4 b0 = *(const float4*)&Bs[132 * k + 4 * tx];
            const float4 b1 = *(const float4*)&Bs[132 * k + 64 + 4 * tx];
            #pragma unroll
            for (int j = 0; j < 8; ++j) {
                acc[j][0] += a[j] * b0.x; acc[j][1] += a[j] * b0.y;
                acc[j][2] += a[j] * b0.z; acc[j][3] += a[j] * b0.w;
                acc[j][4] += a[j] * b1.x; acc[j][5] += a[j] * b1.y;
                acc[j][6] += a[j] * b1.z; acc[j][7] += a[j] * b1.w;
            }
        }
        __syncthreads();
    }

    // epilogue: y = r*acc - r*m*G + B
    const float4 g0 = *(const float4*)&GS[4 * tx];
    const float4 g1 = *(const float4*)&GS[64 + 4 * tx];
    const float4 bb0 = *(const float4*)&BS[4 * tx];
    const float4 bb1 = *(const float4*)&BS[64 + 4 * tx];
    #pragma unroll
    for (int j = 0; j < 8; ++j) {
        const int r = 8 * ty + j;
        const float m = mS[r], rr = rS[r];
        const float rm = rr * m;
        float* dst = y + (((size_t)t * NNODE + rowBase + r) << 7);
        float4 o0, o1;
        o0.x = rr * acc[j][0] - rm * g0.x + bb0.x;
        o0.y = rr * acc[j][1] - rm * g0.y + bb0.y;
        o0.z = rr * acc[j][2] - rm * g0.z + bb0.z;
        o0.w = rr * acc[j][3] - rm * g0.w + bb0.w;
        o1.x = rr * acc[j][4] - rm * g1.x + bb1.x;
        o1.y = rr * acc[j][5] - rm * g1.y + bb1.y;
        o1.z = rr * acc[j][6] - rm * g1.z + bb1.z;
        o1.w = rr * acc[j][7] - rm * g1.w + bb1.w;
        *(float4*)(dst + 4 * tx) = o0;
        *(float4*)(dst + 64 + 4 * tx) = o1;
    }
}

// ---- Kernel 2: per-node sums -> gelu -> chunk sum into sbuf ----
// grid (sub 16, l 16, t 8), block 256 = 2 node-lanes x 128 cols. 128 nodes/block.
__global__ __launch_bounds__(256) void k_node_sum(
    const float* __restrict__ y, const float* __restrict__ b1,
    const int* __restrict__ cnt, const int* __restrict__ slot0,
    const int* __restrict__ slotsx,
    const int* __restrict__ ovfcnt, const int* __restrict__ ovf,
    float* __restrict__ sbuf)
{
    const int tid = threadIdx.x;
    const int sub = blockIdx.x, l = blockIdx.y, t = blockIdx.z;
    const int base = l * CHUNK + sub * 128;

    __shared__ int cS[128], s0S[128];
    __shared__ float redc[256];

    if (tid < 128) {
        cS[tid]  = cnt[t * NNODES + base + tid];
        s0S[tid] = slot0[t * NNODES + base + tid];
    }
    __syncthreads();

    const int c = tid & 127;
    const int h = tid >> 7;
    const float b1c = b1[c];
    const float geluB = gelu_exact(b1c);
    const float* ybase = y + (((size_t)t * NNODE) << 7) + c;

    float cs = 0.f;
    int zc = 0;

    for (int p = 0; p < 64; ++p) {
        const int nl = p * 2 + h;
        const int n = cS[nl];
        if (n == 0) { ++zc; continue; }
        float acc = b1c + ybase[(size_t)s0S[nl] << 7];
        if (n > 1) {
            const int m = n < 16 ? n : 16;
            const int* sx = slotsx + (size_t)(t * NNODES + base + nl) * 15;
            for (int j = 0; j < m - 1; ++j)
                acc += ybase[(size_t)sx[j] << 7];
            if (n > 16) {
                int oc = ovfcnt[t]; if (oc > NNODE) oc = NNODE;
                const int node = base + nl;
                for (int e = 0; e < oc; ++e) {
                    const int v = ovf[t * NNODE + e];
                    if ((v >> 13) == node) acc += ybase[(size_t)(v & 8191) << 7];
                }
            }
        }
        cs += gelu_exact(acc);
    }
    cs += (float)zc * geluB;

    redc[tid] = cs;
    __syncthreads();
    if (tid < 128)
        atomicAdd(&sbuf[(t * CLEN + l) * H1 + c], redc[tid] + redc[tid + 128]);
}

// ---- Kernel 3: comp/lnf/lnd/MLP -> decRow. grid (ch 4, t 8); prelude redundant, ----
// each block writes its own 64-col chunk of dw2 output. 4-way split accumulators.
__global__ __launch_bounds__(256) void k_decode(
    const float* __restrict__ sbuf, const float* __restrict__ w2,
    const float* __restrict__ b2,
    const float* __restrict__ lnf_g, const float* __restrict__ lnf_b,
    const float* __restrict__ lnd_g, const float* __restrict__ lnd_b,
    const float* __restrict__ dw1, const float* __restrict__ db1,
    const float* __restrict__ dw2, const float* __restrict__ db2,
    float* __restrict__ decRow)
{
    const int ch = blockIdx.x, t = blockIdx.y, tid = threadIdx.x;
    __shared__ float wbuf[8192];
    __shared__ float sb[CLEN * H1];
    __shared__ float comp[CLEN * CDIM];
    __shared__ float2 red2[256];
    __shared__ float vv[CLEN][CDIM];
    __shared__ float hh[CLEN][H1];
    __shared__ float mvS[2];
    __shared__ float m2S[CLEN], r2S[CLEN];

    #pragma unroll
    for (int u = 0; u < 2; ++u) {
        const int j4 = (tid + u * 256) * 4;
        if (j4 < CLEN * H1) *(float4*)&sb[j4] = *(const float4*)(sbuf + t * CLEN * H1 + j4);
    }
    #pragma unroll
    for (int u = 0; u < 8; ++u) {
        const int j4 = (tid + u * 256) * 4;
        *(float4*)&wbuf[j4] = *(const float4*)(w2 + j4);
    }
    __syncthreads();

    // 1) comp = sb @ w2 + CHUNK*b2 (4-way chains)
    #pragma unroll
    for (int u = 0; u < 4; ++u) {
        const int j = tid + u * 256;
        const int l = j >> 6, cc = j & 63;
        const float* sp = sb + l * H1;
        float a0 = 0.f, a1 = 0.f, a2 = 0.f, a3 = 0.f;
        for (int k = 0; k < H1; k += 4) {
            a0 += sp[k + 0] * wbuf[(k + 0) * CDIM + cc];
            a1 += sp[k + 1] * wbuf[(k + 1) * CDIM + cc];
            a2 += sp[k + 2] * wbuf[(k + 2) * CDIM + cc];
            a3 += sp[k + 3] * wbuf[(k + 3) * CDIM + cc];
        }
        comp[j] = (float)CHUNK * b2[cc] + ((a0 + a1) + (a2 + a3));
    }
    __syncthreads();
    // 2) lnf over 1024
    {
        float s = 0.f, ss = 0.f;
        #pragma unroll
        for (int u = 0; u < 4; ++u) { const float v = comp[tid + u * 256]; s += v; ss += v * v; }
        red2[tid] = make_float2(s, ss);
        __syncthreads();
        for (int st = 128; st > 0; st >>= 1) {
            if (tid < st) {
                red2[tid].x += red2[tid + st].x;
                red2[tid].y += red2[tid + st].y;
            }
            __syncthreads();
        }
        if (tid == 0) {
            const float m = red2[0].x * (1.0f / 1024.0f);
            const float var = red2[0].y * (1.0f / 1024.0f) - m * m;
            mvS[0] = m; mvS[1] = rsqrtf(var + 1e-5f);
        }
        __syncthreads();
        const float m = mvS[0], r = mvS[1];
        #pragma unroll
        for (int u = 0; u < 4; ++u) {
            const int j = tid + u * 256;
            comp[j] = (comp[j] - m) * r * lnf_g[j] + lnf_b[j];
        }
    }
    __syncthreads();
    // 3) lnd per 64-wide row
    {
        const int l = tid >> 4, q = tid & 15;
        float s = 0.f, ss = 0.f;
        #pragma unroll
        for (int e = 0; e < 4; ++e) {
            const float v = comp[l * CDIM + q * 4 + e];
            s += v; ss += v * v;
        }
        red2[tid] = make_float2(s, ss);
        __syncthreads();
        if (tid < CLEN) {
            float sa = 0.f, sb2 = 0.f;
            for (int k = 0; k < 16; ++k) { sa += red2[tid * 16 + k].x; sb2 += red2[tid * 16 + k].y; }
            const float m = sa * (1.0f / 64.0f);
            const float var = sb2 * (1.0f / 64.0f) - m * m;
            m2S[tid] = m; r2S[tid] = rsqrtf(var + 1e-5f);
        }
        __syncthreads();
        #pragma unroll
        for (int u = 0; u < 4; ++u) {
            const int j = tid + u * 256;
            const int l2 = j >> 6, cc = j & 63;
            vv[l2][cc] = (comp[j] - m2S[l2]) * r2S[l2] * lnd_g[cc] + lnd_b[cc];
        }
    }
    __syncthreads();
    // 4) hh = gelu(vv @ dw1 + db1)
    #pragma unroll
    for (int u = 0; u < 8; ++u) {
        const int j4 = (tid + u * 256) * 4;
        *(float4*)&wbuf[j4] = *(const float4*)(dw1 + j4);
    }
    __syncthreads();
    #pragma unroll
    for (int u = 0; u < 8; ++u) {
        const int j = tid + u * 256;
        const int l = j >> 7, cc = j & 127;
        float a0 = 0.f, a1 = 0.f, a2 = 0.f, a3 = 0.f;
        for (int k = 0; k < CDIM; k += 4) {
            a0 += vv[l][k + 0] * wbuf[(k + 0) * H1 + cc];
            a1 += vv[l][k + 1] * wbuf[(k + 1) * H1 + cc];
            a2 += vv[l][k + 2] * wbuf[(k + 2) * H1 + cc];
            a3 += vv[l][k + 3] * wbuf[(k + 3) * H1 + cc];
        }
        hh[l][cc] = gelu_exact(db1[cc] + ((a0 + a1) + (a2 + a3)));
    }
    __syncthreads();
    // 5) this block's 64-col chunk of decRow = hh @ dw2 + db2
    {
        const int c0 = ch * 64;
        #pragma unroll
        for (int u = 0; u < 8; ++u) {
            const int e = tid + u * 256;
            const int k = e >> 4, cq = e & 15;
            *(float4*)&wbuf[k * 64 + cq * 4] =
                *(const float4*)(dw2 + (size_t)k * DD + c0 + cq * 4);
        }
        __syncthreads();
        #pragma unroll
        for (int u = 0; u < 4; ++u) {
            const int j = tid + u * 256;
            const int l = j >> 6, cc = j & 63;
            float a0 = 0.f, a1 = 0.f, a2 = 0.f, a3 = 0.f;
            for (int k = 0; k < H1; k += 4) {
                a0 += hh[l][k + 0] * wbuf[(k + 0) * 64 + cc];
                a1 += hh[l][k + 1] * wbuf[(k + 1) * 64 + cc];
                a2 += hh[l][k + 2] * wbuf[(k + 2) * 64 + cc];
                a3 += hh[l][k + 3] * wbuf[(k + 3) * 64 + cc];
            }
            decRow[(t * CLEN + l) * DD + c0 + cc] = db2[c0 + cc] + ((a0 + a1) + (a2 + a3));
        }
    }
}

// ---- Kernel 4: out[t,i,:] = decRow[t, idx[t,i]>>11, :] for i<8192 else 0 ----
__global__ __launch_bounds__(256) void k_gather(
    const int* __restrict__ indices, const float* __restrict__ decRow,
    float* __restrict__ out)
{
    const int tid = threadIdx.x;
    const int r = blockIdx.x * 4 + (tid >> 6);
    const int c4 = tid & 63;
    const int t = r / NTOK;
    const int i = r - t * NTOK;
    float4 v = make_float4(0.f, 0.f, 0.f, 0.f);
    if (i < NNODE) {
        const int node = indices[t * NNODE + i];
        const int l = node >> 11;
        v = *(const float4*)(decRow + (t * CLEN + l) * DD + c4 * 4);
    }
    *(float4*)(out + (size_t)r * DD + c4 * 4) = v;
}

extern "C" void kernel_launch(void* const* d_in, const int* in_sizes, int n_in,
                              void* d_out, int out_size, void* d_ws, size_t ws_size,
                              hipStream_t stream)
{
    const float* x       = (const float*)d_in[0];
    const int*   indices = (const int*)d_in[1];
    const float* ln1_g   = (const float*)d_in[2];
    const float* ln1_b   = (const float*)d_in[3];
    const float* w1      = (const float*)d_in[4];
    const float* b1      = (const float*)d_in[5];
    const float* w2      = (const float*)d_in[6];
    const float* b2      = (const float*)d_in[7];
    const float* lnf_g   = (const float*)d_in[8];
    const float* lnf_b   = (const float*)d_in[9];
    const float* lnd_g   = (const float*)d_in[10];
    const float* lnd_b   = (const float*)d_in[11];
    const float* dw1     = (const float*)d_in[12];
    const float* db1     = (const float*)d_in[13];
    const float* dw2     = (const float*)d_in[14];
    const float* db2     = (const float*)d_in[15];
    float* out = (float*)d_out;

    char* ws = (char*)d_ws;
    int*   cnt    = (int*)ws;                            // 0x0000000, 1 MiB
    int*   ovfcnt = (int*)(ws + 0x100000);               // 32 B
    float* sbuf   = (float*)(ws + 0x100020);             // 64 KiB -> 0x110020
    int*   slot0  = (int*)(ws + 0x120000);               // 1 MiB
    int*   slotsx = (int*)(ws + 0x220000);               // 15 MiB -> 0x1120000
    int*   ovf    = (int*)(ws + 0x1120000);              // 256 KiB
    float* decRow = (float*)(ws + 0x1160000);            // 128 KiB
    float* Gv     = (float*)(ws + 0x1180000);            // 512 B
    float* Bv     = (float*)(ws + 0x1180200);            // 512 B
    float* y      = (float*)(ws + 0x1190000);            // 32 MiB

    hipMemsetAsync(ws, 0, 0x110020, stream);             // cnt + ovfcnt + sbuf

    k_prep<<<1, 256, 0, stream>>>(ln1_g, ln1_b, w1, Gv, Bv);
    k_ln_gemm<<<dim3(64, 8), 256, 0, stream>>>(x, indices, ln1_g, w1, Gv, Bv, y,
                                               cnt, slot0, slotsx, ovfcnt, ovf);
    k_node_sum<<<dim3(16, 16, 8), 256, 0, stream>>>(y, b1, cnt, slot0, slotsx,
                                                    ovfcnt, ovf, sbuf);
    k_decode<<<dim3(4, 8), 256, 0, stream>>>(sbuf, w2, b2, lnf_g, lnf_b, lnd_g, lnd_b,
                                             dw1, db1, dw2, db2, decRow);
    k_gather<<<24576, 256, 0, stream>>>(indices, decRow, out);
}